// Round 1
// 2105.296 us; speedup vs baseline: 1.0108x; 1.0108x over previous
//
#include <hip/hip_runtime.h>
#include <cstdint>

typedef unsigned short u16;
typedef _Float16 f16x8  __attribute__((ext_vector_type(8)));
typedef float    f32x4  __attribute__((ext_vector_type(4)));
typedef float    v2f    __attribute__((ext_vector_type(2)));

#define DEV static __device__ __forceinline__

constexpr int kB = 8;     // batches
constexpr int kN = 8192;  // points per batch
constexpr int kS = 2048;  // npoint (FPS centers)
constexpr int kK = 32;    // nsample
constexpr int kC = 64;    // feature channels

DEV v2f vmin2(v2f a, v2f b){ v2f r; r.x = fminf(a.x,b.x); r.y = fminf(a.y,b.y); return r; }

// f32 DPP max step: bound_ctrl=1 zero-fill is harmless (all dists >= 0)
template<int CTRL>
DEV float dppmax(float v){
  int x = __builtin_amdgcn_mov_dpp(__builtin_bit_cast(int, v), CTRL, 0xF, 0xF, true);
  float o = __builtin_bit_cast(float, x);
  return fmaxf(v, o);
}
DEV float readlanef(float v, int l){
  return __builtin_bit_cast(float, __builtin_amdgcn_readlane(__builtin_bit_cast(int, v), l));
}

// ---------------------------------------------------------------------------
// Kernel 0: xyz (B,N,3) f32 -> planar f32 SoA
// ---------------------------------------------------------------------------
__global__ __launch_bounds__(256) void prep_kernel(const float* __restrict__ xyz,
                                                   float* __restrict__ X,
                                                   float* __restrict__ Y,
                                                   float* __restrict__ Z){
  int i = blockIdx.x * 256 + threadIdx.x;
  if (i < kB * kN){
    X[i] = xyz[i*3+0];
    Y[i] = xyz[i*3+1];
    Z[i] = xyz[i*3+2];
  }
}

// ---------------------------------------------------------------------------
// Kernel 1: farthest point sampling. One block per batch (serial argmax chain).
// 512 threads x 16 points in registers. Exact np math: no fma, ((dx2+dy2)+dz2),
// argmax tie-break = smallest index (lanes/waves cover ascending contiguous
// ranges, so ballot+ctz picks the smallest global index among equal maxima).
// amdgpu_waves_per_eu(2,2): only 1 block/CU can be resident (grid == 8), so
// give the allocator the full 2-wave/SIMD VGPR budget (256) and keep
// px/py/pz/dd (64 floats/thread) in registers — the previous build reported
// VGPR_Count=40, i.e. the point arrays were being spilled every iteration.
// ---------------------------------------------------------------------------
__global__ __launch_bounds__(512) __attribute__((amdgpu_waves_per_eu(2, 2)))
void fps_kernel(const float* __restrict__ X,
                const float* __restrict__ Y,
                const float* __restrict__ Z,
                int* __restrict__ cidx,
                float* __restrict__ oxyz){
  const int b    = blockIdx.x;
  const int tid  = threadIdx.x;
  const int lane = tid & 63;
  const int wid  = tid >> 6;          // 8 waves
  __shared__ float sm[2][8];          // per-wave max (double-buffered by t&1)
  __shared__ int   si[2][8];          // per-wave winning point index
  const float* xb = X + b*kN;
  const float* yb = Y + b*kN;
  const float* zb = Z + b*kN;

  v2f px[8], py[8], pz[8], dd[8];
  #pragma unroll
  for (int j = 0; j < 8; j++){
    int p0 = tid*16 + 2*j;
    px[j].x = xb[p0]; px[j].y = xb[p0+1];
    py[j].x = yb[p0]; py[j].y = yb[p0+1];
    pz[j].x = zb[p0]; pz[j].y = zb[p0+1];
    dd[j].x = 1e10f;  dd[j].y = 1e10f;
  }
  float cx = xb[0], cy = yb[0], cz = zb[0];
  if (tid == 0){
    cidx[b*kS] = 0;
    size_t o = (size_t)b*kS*3;
    oxyz[o+0] = cx; oxyz[o+1] = cy; oxyz[o+2] = cz;
  }

  #pragma unroll 1
  for (int t = 1; t < kS; t++){
    // ---- min-dist update (exact np order, no fma) + per-pair max ----
    float q[8];
    {
      #pragma clang fp contract(off)
      v2f c2x; c2x.x = cx; c2x.y = cx;
      v2f c2y; c2y.x = cy; c2y.y = cy;
      v2f c2z; c2z.x = cz; c2z.y = cz;
      #pragma unroll
      for (int j = 0; j < 8; j++){
        v2f dx = px[j] - c2x;
        v2f dy = py[j] - c2y;
        v2f dz = pz[j] - c2z;
        v2f d  = dx*dx + dy*dy;   // (dx^2 + dy^2)
        d = d + dz*dz;            // ... + dz^2  (np sum order, no fma)
        dd[j] = vmin2(dd[j], d);
        q[j]  = fmaxf(dd[j].x, dd[j].y);
      }
    }
    // ---- local max tree (exact max; order-independent) ----
    float m0 = fmaxf(q[0], q[1]);
    float m1 = fmaxf(q[2], q[3]);
    float m2 = fmaxf(q[4], q[5]);
    float m3 = fmaxf(q[6], q[7]);
    float lmax = fmaxf(fmaxf(m0, m1), fmaxf(m2, m3));
    // ---- wave max via f32 DPP (cheap: 2 ops/step) ----
    float r = lmax;
    r = dppmax<0xB1>(r);    // quad_perm(1,0,3,2)
    r = dppmax<0x4E>(r);    // quad_perm(2,3,0,1)
    r = dppmax<0x114>(r);   // row_shr:4
    r = dppmax<0x118>(r);   // row_shr:8
    r = dppmax<0x142>(r);   // row_bcast15
    r = dppmax<0x143>(r);   // row_bcast31
    float wmax = readlanef(r, 63);
    // ---- per-lane arg scan vs wave max (smallest slot wins) ----
    int sl = 16;
    #pragma unroll
    for (int j = 7; j >= 0; j--){
      if (dd[j].y == wmax) sl = 2*j + 1;
      if (dd[j].x == wmax) sl = 2*j;
    }
    // winning lane = smallest lane whose local max equals the wave max
    unsigned long long mk = __ballot(lmax == wmax);
    int wl   = (int)__builtin_ctzll(mk);               // uniform (SGPR)
    int widx = __builtin_amdgcn_readlane(tid*16 + sl, wl);
    if (lane == 0){ sm[t & 1][wid] = wmax; si[t & 1][wid] = widx; }
    __syncthreads();
    // ---- combine 8 wave partials (replicated across lanes, 3 DPP steps) ----
    float m8 = sm[t & 1][lane & 7];
    int   i8 = si[t & 1][lane & 7];
    float r2 = m8;
    r2 = dppmax<0xB1>(r2);
    r2 = dppmax<0x4E>(r2);
    r2 = dppmax<0x114>(r2);
    float bmax = readlanef(r2, 7);
    unsigned long long mk2 = __ballot(m8 == bmax);
    int ww = (int)__builtin_ctzll(mk2);                // smallest wave id
    int w  = __builtin_amdgcn_readlane(i8, ww);        // uniform point index
    cx = xb[w]; cy = yb[w]; cz = zb[w];                // uniform -> scalar load
    if (tid == 0){
      cidx[b*kS + t] = w;
      size_t o = ((size_t)b*kS + t) * 3;
      oxyz[o+0] = cx; oxyz[o+1] = cy; oxyz[o+2] = cz;
    }
  }
}

// ---------------------------------------------------------------------------
// Kernel 2: ball query. One wave per center; ascending-index ballot compaction,
// early exit once 32 found; pad with first index. Exact np math & threshold.
// ---------------------------------------------------------------------------
__global__ __launch_bounds__(256) void ballq_kernel(const float* __restrict__ X,
                                                    const float* __restrict__ Y,
                                                    const float* __restrict__ Z,
                                                    const int* __restrict__ cidx,
                                                    u16* __restrict__ bidx){
  const int lw   = threadIdx.x >> 6;
  const int lane = threadIdx.x & 63;
  const int wv   = blockIdx.x * 4 + lw;     // center id, < 16384 exactly
  __shared__ u16 buf[4][kK];
  const int b = wv >> 11;
  const float* xb = X + b*kN;
  const float* yb = Y + b*kN;
  const float* zb = Z + b*kN;
  const int ci = cidx[wv];
  const float ccx = xb[ci], ccy = yb[ci], ccz = zb[ci];
  const float R2 = (float)(0.2*0.2);        // f32(0.04000000000000001)

  int cnt = 0;
  for (int base = 0; base < kN; base += 64){
    float sq;
    {
      #pragma clang fp contract(off)
      int p = base + lane;
      float dx = xb[p] - ccx;
      float dy = yb[p] - ccy;
      float dz = zb[p] - ccz;
      sq = dx*dx + dy*dy;
      sq = sq + dz*dz;
    }
    bool in = !(sq > R2);                   // ref excludes sqr > r^2
    unsigned long long mk = __ballot(in);
    int pos = cnt + __popcll(mk & ((1ull << lane) - 1ull));
    if (in && pos < kK) buf[lw][pos] = (u16)(base + lane);
    cnt += (int)__popcll(mk);
    if (cnt >= kK) break;                   // cnt is wave-uniform
  }
  u16 first = buf[lw][0];                   // center itself always in-ball
  if (lane < kK){
    int c = cnt < kK ? cnt : kK;
    bidx[(size_t)wv*kK + lane] = (lane < c) ? buf[lw][lane] : first;
  }
}

// ---------------------------------------------------------------------------
// Kernel 3: gather + 3-layer MLP (fp16 MFMA) + max over samples.
// One wave per center (8 centers/wave). Channel order permuted to
// [feats(64), dp(3), 0-pad] so L1 A-fragments load straight from feats with
// aligned f32x4 (permutation applied to W1 too — identical real sum).
// C->A layout transform via per-wave LDS (rows padded to 72 elems).
// ---------------------------------------------------------------------------
DEV f16x8 ld8cvt(const float* p){
  f32x4 a = *(const f32x4*)p;
  f32x4 b = *(const f32x4*)(p + 4);
  f16x8 h;
  #pragma unroll
  for (int j = 0; j < 4; j++){ h[j] = (_Float16)a[j]; h[4+j] = (_Float16)b[j]; }
  return h;
}

__global__ __launch_bounds__(256) void mlp_kernel(
    const float* __restrict__ feats,
    const float* __restrict__ w1, const float* __restrict__ b1, const float* __restrict__ g1, const float* __restrict__ bt1,
    const float* __restrict__ w2, const float* __restrict__ b2, const float* __restrict__ g2, const float* __restrict__ bt2,
    const float* __restrict__ w3, const float* __restrict__ b3, const float* __restrict__ g3, const float* __restrict__ bt3,
    const float* __restrict__ X, const float* __restrict__ Y, const float* __restrict__ Z,
    const int* __restrict__ cidx, const u16* __restrict__ bidx,
    float* __restrict__ ofeat)
{
  constexpr int HP = 72;                       // padded LDS row (elems)
  __shared__ _Float16 H[4][32*HP];             // per-wave activation buffer
  const int lw   = threadIdx.x >> 6;
  const int lane = threadIdx.x & 63;
  const int nl   = lane & 15;                  // MFMA n / m / col slot
  const int kg   = lane >> 4;                  // k-group (0..3)
  const int gw   = blockIdx.x * 4 + lw;        // global wave, < 2048
  const float INVS = 0.99999500003749968f;     // 1/sqrt(1+1e-5)

  // --- weight fragments in registers (B-layout: lane holds W[n][k0..k0+7]) ---
  f16x8 wf1[4][3];
  #pragma unroll
  for (int nt = 0; nt < 4; nt++){
    #pragma unroll
    for (int kt = 0; kt < 3; kt++){
      f16x8 h;
      #pragma unroll
      for (int j = 0; j < 8; j++){
        int k = kt*32 + kg*8 + j;
        int c = (k < 64) ? (k + 3) : ((k < 67) ? (k - 64) : -1);  // channel perm
        h[j] = (c >= 0) ? (_Float16)w1[(nt*16 + nl)*67 + c] : (_Float16)0.0f;
      }
      wf1[nt][kt] = h;
    }
  }
  f16x8 wf2[4][2];
  #pragma unroll
  for (int nt = 0; nt < 4; nt++)
    #pragma unroll
    for (int kt = 0; kt < 2; kt++)
      wf2[nt][kt] = ld8cvt(w2 + (nt*16 + nl)*64 + kt*32 + kg*8);
  f16x8 wf3[8][2];
  #pragma unroll
  for (int nt = 0; nt < 8; nt++)
    #pragma unroll
    for (int kt = 0; kt < 2; kt++)
      wf3[nt][kt] = ld8cvt(w3 + (nt*16 + nl)*64 + kt*32 + kg*8);

  // fused BN constants per output column (col = nt*16 + nl in C-layout)
  float a1c[4], e1c[4], a2c[4], e2c[4], a3c[8], e3c[8];
  #pragma unroll
  for (int nt = 0; nt < 4; nt++){
    int c = nt*16 + nl;
    a1c[nt] = g1[c] * INVS; e1c[nt] = fmaf(a1c[nt], b1[c], bt1[c]);
    a2c[nt] = g2[c] * INVS; e2c[nt] = fmaf(a2c[nt], b2[c], bt2[c]);
  }
  #pragma unroll
  for (int nt = 0; nt < 8; nt++){
    int c = nt*16 + nl;
    a3c[nt] = g3[c] * INVS; e3c[nt] = fmaf(a3c[nt], b3[c], bt3[c]);
  }

  _Float16* Hw = &H[lw][0];
  const f32x4 z4 = {0.f, 0.f, 0.f, 0.f};

  #pragma unroll 1
  for (int i = 0; i < 8; i++){
    const int cid = gw*8 + i;
    const int b   = cid >> 11;
    const float* fb = feats + (size_t)b * kN * kC;

    int my = (int)bidx[(size_t)cid*kK + (lane & 31)];   // sample (lane&31)'s point
    int n0 = __shfl(my, nl);
    int n1 = __shfl(my, 16 + nl);
    // L1 A-fragments straight from feats (channels 0..63 = k 0..63)
    f16x8 a00 = ld8cvt(fb + (size_t)n0*kC +      kg*8);
    f16x8 a01 = ld8cvt(fb + (size_t)n0*kC + 32 + kg*8);
    f16x8 a10 = ld8cvt(fb + (size_t)n1*kC +      kg*8);
    f16x8 a11 = ld8cvt(fb + (size_t)n1*kC + 32 + kg*8);
    // dp fragment (k = 64,65,66)
    const float* xb = X + b*kN; const float* yb = Y + b*kN; const float* zb = Z + b*kN;
    int ci = cidx[cid];
    float ccx = xb[ci], ccy = yb[ci], ccz = zb[ci];
    float dpx = (xb[my] - ccx) / 0.2f;
    float dpy = (yb[my] - ccy) / 0.2f;
    float dpz = (zb[my] - ccz) / 0.2f;
    float x0 = __shfl(dpx, nl),      y0 = __shfl(dpy, nl),      zz0 = __shfl(dpz, nl);
    float x1 = __shfl(dpx, 16 + nl), y1 = __shfl(dpy, 16 + nl), zz1 = __shfl(dpz, 16 + nl);
    f16x8 ad0 = {0,0,0,0,0,0,0,0}, ad1 = {0,0,0,0,0,0,0,0};
    if (kg == 0){
      ad0[0] = (_Float16)x0; ad0[1] = (_Float16)y0; ad0[2] = (_Float16)zz0;
      ad1[0] = (_Float16)x1; ad1[1] = (_Float16)y1; ad1[2] = (_Float16)zz1;
    }

    // ---- layer 1 (fp16 MFMA) ----
    f32x4 c1[2][4];
    #pragma unroll
    for (int nt = 0; nt < 4; nt++){
      f32x4 acc = z4;
      acc = __builtin_amdgcn_mfma_f32_16x16x32_f16(ad0, wf1[nt][2], acc, 0, 0, 0);
      acc = __builtin_amdgcn_mfma_f32_16x16x32_f16(a00, wf1[nt][0], acc, 0, 0, 0);
      acc = __builtin_amdgcn_mfma_f32_16x16x32_f16(a01, wf1[nt][1], acc, 0, 0, 0);
      c1[0][nt] = acc;
      acc = z4;
      acc = __builtin_amdgcn_mfma_f32_16x16x32_f16(ad1, wf1[nt][2], acc, 0, 0, 0);
      acc = __builtin_amdgcn_mfma_f32_16x16x32_f16(a10, wf1[nt][0], acc, 0, 0, 0);
      acc = __builtin_amdgcn_mfma_f32_16x16x32_f16(a11, wf1[nt][1], acc, 0, 0, 0);
      c1[1][nt] = acc;
    }
    #pragma unroll
    for (int mt = 0; mt < 2; mt++)
      #pragma unroll
      for (int nt = 0; nt < 4; nt++)
        #pragma unroll
        for (int r = 0; r < 4; r++){
          float h = fmaxf(fmaf(a1c[nt], c1[mt][nt][r], e1c[nt]), 0.f);
          Hw[(mt*16 + kg*4 + r)*HP + nt*16 + nl] = (_Float16)h;   // C-layout
        }
    // ---- layer 2 ----
    f16x8 h1[2][2];
    #pragma unroll
    for (int mt = 0; mt < 2; mt++)
      #pragma unroll
      for (int kt = 0; kt < 2; kt++)
        h1[mt][kt] = *(const f16x8*)(Hw + (mt*16 + nl)*HP + kt*32 + kg*8);
    f32x4 c2[2][4];
    #pragma unroll
    for (int mt = 0; mt < 2; mt++)
      #pragma unroll
      for (int nt = 0; nt < 4; nt++){
        f32x4 acc = z4;
        acc = __builtin_amdgcn_mfma_f32_16x16x32_f16(h1[mt][0], wf2[nt][0], acc, 0, 0, 0);
        acc = __builtin_amdgcn_mfma_f32_16x16x32_f16(h1[mt][1], wf2[nt][1], acc, 0, 0, 0);
        c2[mt][nt] = acc;
      }
    #pragma unroll
    for (int mt = 0; mt < 2; mt++)
      #pragma unroll
      for (int nt = 0; nt < 4; nt++)
        #pragma unroll
        for (int r = 0; r < 4; r++){
          float h = fmaxf(fmaf(a2c[nt], c2[mt][nt][r], e2c[nt]), 0.f);
          Hw[(mt*16 + kg*4 + r)*HP + nt*16 + nl] = (_Float16)h;
        }
    // ---- layer 3 + max over 32 samples + store ----
    f16x8 h2[2][2];
    #pragma unroll
    for (int mt = 0; mt < 2; mt++)
      #pragma unroll
      for (int kt = 0; kt < 2; kt++)
        h2[mt][kt] = *(const f16x8*)(Hw + (mt*16 + nl)*HP + kt*32 + kg*8);
    #pragma unroll
    for (int nt = 0; nt < 8; nt++){
      f32x4 d0 = z4, d1 = z4;
      d0 = __builtin_amdgcn_mfma_f32_16x16x32_f16(h2[0][0], wf3[nt][0], d0, 0, 0, 0);
      d0 = __builtin_amdgcn_mfma_f32_16x16x32_f16(h2[0][1], wf3[nt][1], d0, 0, 0, 0);
      d1 = __builtin_amdgcn_mfma_f32_16x16x32_f16(h2[1][0], wf3[nt][0], d1, 0, 0, 0);
      d1 = __builtin_amdgcn_mfma_f32_16x16x32_f16(h2[1][1], wf3[nt][1], d1, 0, 0, 0);
      float m = -1e30f;
      #pragma unroll
      for (int r = 0; r < 4; r++){
        m = fmaxf(m, fmaf(a3c[nt], d0[r], e3c[nt]));
        m = fmaxf(m, fmaf(a3c[nt], d1[r], e3c[nt]));
      }
      m = fmaxf(m, 0.f);                       // relu(max) == max(relu)
      m = fmaxf(m, __shfl_xor(m, 16));
      m = fmaxf(m, __shfl_xor(m, 32));
      if (lane < 16) ofeat[(size_t)cid*128 + nt*16 + nl] = m;
    }
  }
}

// ---------------------------------------------------------------------------
// launch: prep -> fps -> ball query -> mlp   (all on `stream`, graph-safe)
// ws: X,Y,Z f32[65536 each] | center_idx int[16384] | ball idx u16[16384*32]
// ---------------------------------------------------------------------------
extern "C" void kernel_launch(void* const* d_in, const int* in_sizes, int n_in,
                              void* d_out, int out_size, void* d_ws, size_t ws_size,
                              hipStream_t stream){
  (void)in_sizes; (void)n_in; (void)out_size; (void)ws_size;
  const float* xyz   = (const float*)d_in[0];
  const float* feats = (const float*)d_in[1];
  const float* w1  = (const float*)d_in[2];
  const float* b1  = (const float*)d_in[3];
  const float* g1  = (const float*)d_in[4];
  const float* bt1 = (const float*)d_in[5];
  const float* w2  = (const float*)d_in[6];
  const float* b2  = (const float*)d_in[7];
  const float* g2  = (const float*)d_in[8];
  const float* bt2 = (const float*)d_in[9];
  const float* w3  = (const float*)d_in[10];
  const float* b3  = (const float*)d_in[11];
  const float* g3  = (const float*)d_in[12];
  const float* bt3 = (const float*)d_in[13];
  float* out = (float*)d_out;

  float* X  = (float*)d_ws;
  float* Y  = X + kB*kN;
  float* Z  = Y + kB*kN;
  int*   ci = (int*)(Z + kB*kN);
  u16*   bi = (u16*)(ci + kB*kS);

  hipLaunchKernelGGL(prep_kernel,  dim3(256),  dim3(256), 0, stream, xyz, X, Y, Z);
  hipLaunchKernelGGL(fps_kernel,   dim3(kB),   dim3(512), 0, stream, X, Y, Z, ci, out);
  hipLaunchKernelGGL(ballq_kernel, dim3(4096), dim3(256), 0, stream, X, Y, Z, ci, bi);
  hipLaunchKernelGGL(mlp_kernel,   dim3(512),  dim3(256), 0, stream,
                     feats, w1, b1, g1, bt1, w2, b2, g2, bt2, w3, b3, g3, bt3,
                     X, Y, Z, ci, bi, out + (size_t)kB*kS*3);
}

// Round 2
// 1879.039 us; speedup vs baseline: 1.1325x; 1.1204x over previous
//
#include <hip/hip_runtime.h>
#include <cstdint>

typedef unsigned short u16;
typedef _Float16 f16x8  __attribute__((ext_vector_type(8)));
typedef float    f32x4  __attribute__((ext_vector_type(4)));
typedef float    v2f    __attribute__((ext_vector_type(2)));

#define DEV static __device__ __forceinline__

constexpr int kB = 8;     // batches
constexpr int kN = 8192;  // points per batch
constexpr int kS = 2048;  // npoint (FPS centers)
constexpr int kK = 32;    // nsample
constexpr int kC = 64;    // feature channels

DEV v2f vmin2(v2f a, v2f b){ v2f r; r.x = fminf(a.x,b.x); r.y = fminf(a.y,b.y); return r; }

// f32 DPP max step: bound_ctrl=1 zero-fill is harmless (all dists >= 0)
template<int CTRL>
DEV float dppmax(float v){
  int x = __builtin_amdgcn_mov_dpp(__builtin_bit_cast(int, v), CTRL, 0xF, 0xF, true);
  float o = __builtin_bit_cast(float, x);
  return fmaxf(v, o);
}
DEV float readlanef(float v, int l){
  return __builtin_bit_cast(float, __builtin_amdgcn_readlane(__builtin_bit_cast(int, v), l));
}

// ---------------------------------------------------------------------------
// Kernel 0: xyz (B,N,3) f32 -> planar f32 SoA
// ---------------------------------------------------------------------------
__global__ __launch_bounds__(256) void prep_kernel(const float* __restrict__ xyz,
                                                   float* __restrict__ X,
                                                   float* __restrict__ Y,
                                                   float* __restrict__ Z){
  int i = blockIdx.x * 256 + threadIdx.x;
  if (i < kB * kN){
    X[i] = xyz[i*3+0];
    Y[i] = xyz[i*3+1];
    Z[i] = xyz[i*3+2];
  }
}

// ---------------------------------------------------------------------------
// Kernel 1: farthest point sampling. One block per batch (serial argmax chain).
// 512 threads x 16 points in registers. Exact np math: no fma, ((dx2+dy2)+dz2),
// argmax tie-break = smallest index (lanes/waves cover ascending contiguous
// ranges; ctz(ballot) picks smallest lane/wave; within-lane desc scan picks
// smallest slot). Batch xyz is mirrored in LDS (96 KB) so the per-iteration
// uniform center fetch is an LDS broadcast (~120 cy) instead of a global/L2
// round trip (~300-900 cy) on the serial argmax->distance dependency chain.
// ---------------------------------------------------------------------------
__global__ __launch_bounds__(512) __attribute__((amdgpu_waves_per_eu(2, 2)))
void fps_kernel(const float* __restrict__ X,
                const float* __restrict__ Y,
                const float* __restrict__ Z,
                int* __restrict__ cidx,
                float* __restrict__ oxyz){
  __shared__ __align__(16) float lx[kN];
  __shared__ __align__(16) float ly[kN];
  __shared__ __align__(16) float lz[kN];
  __shared__ uint64_t sk[2][8];       // per-wave packed {dist_bits, idx}
  const int b    = blockIdx.x;
  const int tid  = threadIdx.x;
  const int lane = tid & 63;
  const int wid  = tid >> 6;          // 8 waves
  const float* xb = X + b*kN;
  const float* yb = Y + b*kN;
  const float* zb = Z + b*kN;

  v2f px[8], py[8], pz[8], dd[8];
  const int p0 = tid*16;
  {
    f32x4 t0 = *(const f32x4*)(xb+p0);   f32x4 t1 = *(const f32x4*)(xb+p0+4);
    f32x4 t2 = *(const f32x4*)(xb+p0+8); f32x4 t3 = *(const f32x4*)(xb+p0+12);
    *(f32x4*)(lx+p0)=t0; *(f32x4*)(lx+p0+4)=t1; *(f32x4*)(lx+p0+8)=t2; *(f32x4*)(lx+p0+12)=t3;
    px[0]=(v2f){t0.x,t0.y}; px[1]=(v2f){t0.z,t0.w}; px[2]=(v2f){t1.x,t1.y}; px[3]=(v2f){t1.z,t1.w};
    px[4]=(v2f){t2.x,t2.y}; px[5]=(v2f){t2.z,t2.w}; px[6]=(v2f){t3.x,t3.y}; px[7]=(v2f){t3.z,t3.w};
  }
  {
    f32x4 t0 = *(const f32x4*)(yb+p0);   f32x4 t1 = *(const f32x4*)(yb+p0+4);
    f32x4 t2 = *(const f32x4*)(yb+p0+8); f32x4 t3 = *(const f32x4*)(yb+p0+12);
    *(f32x4*)(ly+p0)=t0; *(f32x4*)(ly+p0+4)=t1; *(f32x4*)(ly+p0+8)=t2; *(f32x4*)(ly+p0+12)=t3;
    py[0]=(v2f){t0.x,t0.y}; py[1]=(v2f){t0.z,t0.w}; py[2]=(v2f){t1.x,t1.y}; py[3]=(v2f){t1.z,t1.w};
    py[4]=(v2f){t2.x,t2.y}; py[5]=(v2f){t2.z,t2.w}; py[6]=(v2f){t3.x,t3.y}; py[7]=(v2f){t3.z,t3.w};
  }
  {
    f32x4 t0 = *(const f32x4*)(zb+p0);   f32x4 t1 = *(const f32x4*)(zb+p0+4);
    f32x4 t2 = *(const f32x4*)(zb+p0+8); f32x4 t3 = *(const f32x4*)(zb+p0+12);
    *(f32x4*)(lz+p0)=t0; *(f32x4*)(lz+p0+4)=t1; *(f32x4*)(lz+p0+8)=t2; *(f32x4*)(lz+p0+12)=t3;
    pz[0]=(v2f){t0.x,t0.y}; pz[1]=(v2f){t0.z,t0.w}; pz[2]=(v2f){t1.x,t1.y}; pz[3]=(v2f){t1.z,t1.w};
    pz[4]=(v2f){t2.x,t2.y}; pz[5]=(v2f){t2.z,t2.w}; pz[6]=(v2f){t3.x,t3.y}; pz[7]=(v2f){t3.z,t3.w};
  }
  #pragma unroll
  for (int j = 0; j < 8; j++){ dd[j].x = 1e10f; dd[j].y = 1e10f; }

  __syncthreads();
  float cx = lx[0], cy = ly[0], cz = lz[0];
  if (tid == 0){
    cidx[b*kS] = 0;
    size_t o = (size_t)b*kS*3;
    oxyz[o+0] = cx; oxyz[o+1] = cy; oxyz[o+2] = cz;
  }

  #pragma unroll 1
  for (int t = 1; t < kS; t++){
    // ---- min-dist update (exact np order, no fma) + per-pair max ----
    float q[8];
    {
      #pragma clang fp contract(off)
      v2f c2x; c2x.x = cx; c2x.y = cx;
      v2f c2y; c2y.x = cy; c2y.y = cy;
      v2f c2z; c2z.x = cz; c2z.y = cz;
      #pragma unroll
      for (int j = 0; j < 8; j++){
        v2f dx = px[j] - c2x;
        v2f dy = py[j] - c2y;
        v2f dz = pz[j] - c2z;
        v2f d  = dx*dx + dy*dy;   // (dx^2 + dy^2)
        d = d + dz*dz;            // ... + dz^2  (np sum order, no fma)
        dd[j] = vmin2(dd[j], d);
        q[j]  = fmaxf(dd[j].x, dd[j].y);
      }
    }
    // ---- local max tree (exact max; order-independent) ----
    float m0 = fmaxf(q[0], q[1]);
    float m1 = fmaxf(q[2], q[3]);
    float m2 = fmaxf(q[4], q[5]);
    float m3 = fmaxf(q[6], q[7]);
    float lmax = fmaxf(fmaxf(m0, m1), fmaxf(m2, m3));
    // ---- local arg scan vs lmax (smallest slot wins); only the winning
    //      lane's sl is consumed, and there lmax == wmax. Independent of the
    //      DPP chain so it can overlap. ----
    int sl = 0;
    #pragma unroll
    for (int j = 7; j >= 0; j--){
      if (dd[j].y == lmax) sl = 2*j + 1;
      if (dd[j].x == lmax) sl = 2*j;
    }
    // ---- wave max via f32 DPP (2 ops/step) ----
    float r = lmax;
    r = dppmax<0xB1>(r);    // quad_perm(1,0,3,2)
    r = dppmax<0x4E>(r);    // quad_perm(2,3,0,1)
    r = dppmax<0x114>(r);   // row_shr:4
    r = dppmax<0x118>(r);   // row_shr:8
    r = dppmax<0x142>(r);   // row_bcast15
    r = dppmax<0x143>(r);   // row_bcast31
    float wmax = readlanef(r, 63);
    // winning lane = smallest lane whose local max equals the wave max
    unsigned long long mk = __ballot(lmax == wmax);
    int wl   = (int)__builtin_ctzll(mk);               // uniform (SGPR)
    int widx = __builtin_amdgcn_readlane(tid*16 + sl, wl);
    if (lane == 0)
      sk[t & 1][wid] = ((uint64_t)__builtin_bit_cast(uint32_t, wmax) << 32)
                     | (uint32_t)widx;
    __syncthreads();
    // ---- combine 8 wave partials (replicated across lanes, 3 DPP steps) ----
    uint64_t kk = sk[t & 1][lane & 7];
    float m8 = __builtin_bit_cast(float, (uint32_t)(kk >> 32));
    int   i8 = (int)(uint32_t)kk;
    float r2 = m8;
    r2 = dppmax<0xB1>(r2);
    r2 = dppmax<0x4E>(r2);
    r2 = dppmax<0x114>(r2);
    float bmax = readlanef(r2, 7);
    unsigned long long mk2 = __ballot(m8 == bmax);
    int ww = (int)__builtin_ctzll(mk2);                // smallest wave id
    int w  = __builtin_amdgcn_readlane(i8, ww);        // uniform point index
    cx = lx[w]; cy = ly[w]; cz = lz[w];                // uniform LDS broadcast
    if (tid == 0){
      cidx[b*kS + t] = w;
      size_t o = ((size_t)b*kS + t) * 3;
      oxyz[o+0] = cx; oxyz[o+1] = cy; oxyz[o+2] = cz;
    }
  }
}

// ---------------------------------------------------------------------------
// Kernel 2: ball query. One wave per center; ascending-index ballot compaction,
// early exit once 32 found; pad with first index. Exact np math & threshold.
// ---------------------------------------------------------------------------
__global__ __launch_bounds__(256) void ballq_kernel(const float* __restrict__ X,
                                                    const float* __restrict__ Y,
                                                    const float* __restrict__ Z,
                                                    const int* __restrict__ cidx,
                                                    u16* __restrict__ bidx){
  const int lw   = threadIdx.x >> 6;
  const int lane = threadIdx.x & 63;
  const int wv   = blockIdx.x * 4 + lw;     // center id, < 16384 exactly
  __shared__ u16 buf[4][kK];
  const int b = wv >> 11;
  const float* xb = X + b*kN;
  const float* yb = Y + b*kN;
  const float* zb = Z + b*kN;
  const int ci = cidx[wv];
  const float ccx = xb[ci], ccy = yb[ci], ccz = zb[ci];
  const float R2 = (float)(0.2*0.2);        // f32(0.04000000000000001)

  int cnt = 0;
  for (int base = 0; base < kN; base += 64){
    float sq;
    {
      #pragma clang fp contract(off)
      int p = base + lane;
      float dx = xb[p] - ccx;
      float dy = yb[p] - ccy;
      float dz = zb[p] - ccz;
      sq = dx*dx + dy*dy;
      sq = sq + dz*dz;
    }
    bool in = !(sq > R2);                   // ref excludes sqr > r^2
    unsigned long long mk = __ballot(in);
    int pos = cnt + __popcll(mk & ((1ull << lane) - 1ull));
    if (in && pos < kK) buf[lw][pos] = (u16)(base + lane);
    cnt += (int)__popcll(mk);
    if (cnt >= kK) break;                   // cnt is wave-uniform
  }
  u16 first = buf[lw][0];                   // center itself always in-ball
  if (lane < kK){
    int c = cnt < kK ? cnt : kK;
    bidx[(size_t)wv*kK + lane] = (lane < c) ? buf[lw][lane] : first;
  }
}

// ---------------------------------------------------------------------------
// Kernel 3: gather + 3-layer MLP (fp16 MFMA) + max over samples.
// One wave per center (8 centers/wave). Channel order permuted to
// [feats(64), dp(3), 0-pad] so L1 A-fragments load straight from feats with
// aligned f32x4 (permutation applied to W1 too — identical real sum).
// C->A layout transform via per-wave LDS (rows padded to 72 elems).
// ---------------------------------------------------------------------------
DEV f16x8 ld8cvt(const float* p){
  f32x4 a = *(const f32x4*)p;
  f32x4 b = *(const f32x4*)(p + 4);
  f16x8 h;
  #pragma unroll
  for (int j = 0; j < 4; j++){ h[j] = (_Float16)a[j]; h[4+j] = (_Float16)b[j]; }
  return h;
}

__global__ __launch_bounds__(256) void mlp_kernel(
    const float* __restrict__ feats,
    const float* __restrict__ w1, const float* __restrict__ b1, const float* __restrict__ g1, const float* __restrict__ bt1,
    const float* __restrict__ w2, const float* __restrict__ b2, const float* __restrict__ g2, const float* __restrict__ bt2,
    const float* __restrict__ w3, const float* __restrict__ b3, const float* __restrict__ g3, const float* __restrict__ bt3,
    const float* __restrict__ X, const float* __restrict__ Y, const float* __restrict__ Z,
    const int* __restrict__ cidx, const u16* __restrict__ bidx,
    float* __restrict__ ofeat)
{
  constexpr int HP = 72;                       // padded LDS row (elems)
  __shared__ _Float16 H[4][32*HP];             // per-wave activation buffer
  const int lw   = threadIdx.x >> 6;
  const int lane = threadIdx.x & 63;
  const int nl   = lane & 15;                  // MFMA n / m / col slot
  const int kg   = lane >> 4;                  // k-group (0..3)
  const int gw   = blockIdx.x * 4 + lw;        // global wave, < 2048
  const float INVS = 0.99999500003749968f;     // 1/sqrt(1+1e-5)

  // --- weight fragments in registers (B-layout: lane holds W[n][k0..k0+7]) ---
  f16x8 wf1[4][3];
  #pragma unroll
  for (int nt = 0; nt < 4; nt++){
    #pragma unroll
    for (int kt = 0; kt < 3; kt++){
      f16x8 h;
      #pragma unroll
      for (int j = 0; j < 8; j++){
        int k = kt*32 + kg*8 + j;
        int c = (k < 64) ? (k + 3) : ((k < 67) ? (k - 64) : -1);  // channel perm
        h[j] = (c >= 0) ? (_Float16)w1[(nt*16 + nl)*67 + c] : (_Float16)0.0f;
      }
      wf1[nt][kt] = h;
    }
  }
  f16x8 wf2[4][2];
  #pragma unroll
  for (int nt = 0; nt < 4; nt++)
    #pragma unroll
    for (int kt = 0; kt < 2; kt++)
      wf2[nt][kt] = ld8cvt(w2 + (nt*16 + nl)*64 + kt*32 + kg*8);
  f16x8 wf3[8][2];
  #pragma unroll
  for (int nt = 0; nt < 8; nt++)
    #pragma unroll
    for (int kt = 0; kt < 2; kt++)
      wf3[nt][kt] = ld8cvt(w3 + (nt*16 + nl)*64 + kt*32 + kg*8);

  // fused BN constants per output column (col = nt*16 + nl in C-layout)
  float a1c[4], e1c[4], a2c[4], e2c[4], a3c[8], e3c[8];
  #pragma unroll
  for (int nt = 0; nt < 4; nt++){
    int c = nt*16 + nl;
    a1c[nt] = g1[c] * INVS; e1c[nt] = fmaf(a1c[nt], b1[c], bt1[c]);
    a2c[nt] = g2[c] * INVS; e2c[nt] = fmaf(a2c[nt], b2[c], bt2[c]);
  }
  #pragma unroll
  for (int nt = 0; nt < 8; nt++){
    int c = nt*16 + nl;
    a3c[nt] = g3[c] * INVS; e3c[nt] = fmaf(a3c[nt], b3[c], bt3[c]);
  }

  _Float16* Hw = &H[lw][0];
  const f32x4 z4 = {0.f, 0.f, 0.f, 0.f};

  #pragma unroll 1
  for (int i = 0; i < 8; i++){
    const int cid = gw*8 + i;
    const int b   = cid >> 11;
    const float* fb = feats + (size_t)b * kN * kC;

    int my = (int)bidx[(size_t)cid*kK + (lane & 31)];   // sample (lane&31)'s point
    int n0 = __shfl(my, nl);
    int n1 = __shfl(my, 16 + nl);
    // L1 A-fragments straight from feats (channels 0..63 = k 0..63)
    f16x8 a00 = ld8cvt(fb + (size_t)n0*kC +      kg*8);
    f16x8 a01 = ld8cvt(fb + (size_t)n0*kC + 32 + kg*8);
    f16x8 a10 = ld8cvt(fb + (size_t)n1*kC +      kg*8);
    f16x8 a11 = ld8cvt(fb + (size_t)n1*kC + 32 + kg*8);
    // dp fragment (k = 64,65,66)
    const float* xb = X + b*kN; const float* yb = Y + b*kN; const float* zb = Z + b*kN;
    int ci = cidx[cid];
    float ccx = xb[ci], ccy = yb[ci], ccz = zb[ci];
    float dpx = (xb[my] - ccx) / 0.2f;
    float dpy = (yb[my] - ccy) / 0.2f;
    float dpz = (zb[my] - ccz) / 0.2f;
    float x0 = __shfl(dpx, nl),      y0 = __shfl(dpy, nl),      zz0 = __shfl(dpz, nl);
    float x1 = __shfl(dpx, 16 + nl), y1 = __shfl(dpy, 16 + nl), zz1 = __shfl(dpz, 16 + nl);
    f16x8 ad0 = {0,0,0,0,0,0,0,0}, ad1 = {0,0,0,0,0,0,0,0};
    if (kg == 0){
      ad0[0] = (_Float16)x0; ad0[1] = (_Float16)y0; ad0[2] = (_Float16)zz0;
      ad1[0] = (_Float16)x1; ad1[1] = (_Float16)y1; ad1[2] = (_Float16)zz1;
    }

    // ---- layer 1 (fp16 MFMA) ----
    f32x4 c1[2][4];
    #pragma unroll
    for (int nt = 0; nt < 4; nt++){
      f32x4 acc = z4;
      acc = __builtin_amdgcn_mfma_f32_16x16x32_f16(ad0, wf1[nt][2], acc, 0, 0, 0);
      acc = __builtin_amdgcn_mfma_f32_16x16x32_f16(a00, wf1[nt][0], acc, 0, 0, 0);
      acc = __builtin_amdgcn_mfma_f32_16x16x32_f16(a01, wf1[nt][1], acc, 0, 0, 0);
      c1[0][nt] = acc;
      acc = z4;
      acc = __builtin_amdgcn_mfma_f32_16x16x32_f16(ad1, wf1[nt][2], acc, 0, 0, 0);
      acc = __builtin_amdgcn_mfma_f32_16x16x32_f16(a10, wf1[nt][0], acc, 0, 0, 0);
      acc = __builtin_amdgcn_mfma_f32_16x16x32_f16(a11, wf1[nt][1], acc, 0, 0, 0);
      c1[1][nt] = acc;
    }
    #pragma unroll
    for (int mt = 0; mt < 2; mt++)
      #pragma unroll
      for (int nt = 0; nt < 4; nt++)
        #pragma unroll
        for (int r = 0; r < 4; r++){
          float h = fmaxf(fmaf(a1c[nt], c1[mt][nt][r], e1c[nt]), 0.f);
          Hw[(mt*16 + kg*4 + r)*HP + nt*16 + nl] = (_Float16)h;   // C-layout
        }
    // ---- layer 2 ----
    f16x8 h1[2][2];
    #pragma unroll
    for (int mt = 0; mt < 2; mt++)
      #pragma unroll
      for (int kt = 0; kt < 2; kt++)
        h1[mt][kt] = *(const f16x8*)(Hw + (mt*16 + nl)*HP + kt*32 + kg*8);
    f32x4 c2[2][4];
    #pragma unroll
    for (int mt = 0; mt < 2; mt++)
      #pragma unroll
      for (int nt = 0; nt < 4; nt++){
        f32x4 acc = z4;
        acc = __builtin_amdgcn_mfma_f32_16x16x32_f16(h1[mt][0], wf2[nt][0], acc, 0, 0, 0);
        acc = __builtin_amdgcn_mfma_f32_16x16x32_f16(h1[mt][1], wf2[nt][1], acc, 0, 0, 0);
        c2[mt][nt] = acc;
      }
    #pragma unroll
    for (int mt = 0; mt < 2; mt++)
      #pragma unroll
      for (int nt = 0; nt < 4; nt++)
        #pragma unroll
        for (int r = 0; r < 4; r++){
          float h = fmaxf(fmaf(a2c[nt], c2[mt][nt][r], e2c[nt]), 0.f);
          Hw[(mt*16 + kg*4 + r)*HP + nt*16 + nl] = (_Float16)h;
        }
    // ---- layer 3 + max over 32 samples + store ----
    f16x8 h2[2][2];
    #pragma unroll
    for (int mt = 0; mt < 2; mt++)
      #pragma unroll
      for (int kt = 0; kt < 2; kt++)
        h2[mt][kt] = *(const f16x8*)(Hw + (mt*16 + nl)*HP + kt*32 + kg*8);
    #pragma unroll
    for (int nt = 0; nt < 8; nt++){
      f32x4 d0 = z4, d1 = z4;
      d0 = __builtin_amdgcn_mfma_f32_16x16x32_f16(h2[0][0], wf3[nt][0], d0, 0, 0, 0);
      d0 = __builtin_amdgcn_mfma_f32_16x16x32_f16(h2[0][1], wf3[nt][1], d0, 0, 0, 0);
      d1 = __builtin_amdgcn_mfma_f32_16x16x32_f16(h2[1][0], wf3[nt][0], d1, 0, 0, 0);
      d1 = __builtin_amdgcn_mfma_f32_16x16x32_f16(h2[1][1], wf3[nt][1], d1, 0, 0, 0);
      float m = -1e30f;
      #pragma unroll
      for (int r = 0; r < 4; r++){
        m = fmaxf(m, fmaf(a3c[nt], d0[r], e3c[nt]));
        m = fmaxf(m, fmaf(a3c[nt], d1[r], e3c[nt]));
      }
      m = fmaxf(m, 0.f);                       // relu(max) == max(relu)
      m = fmaxf(m, __shfl_xor(m, 16));
      m = fmaxf(m, __shfl_xor(m, 32));
      if (lane < 16) ofeat[(size_t)cid*128 + nt*16 + nl] = m;
    }
  }
}

// ---------------------------------------------------------------------------
// launch: prep -> fps -> ball query -> mlp   (all on `stream`, graph-safe)
// ws: X,Y,Z f32[65536 each] | center_idx int[16384] | ball idx u16[16384*32]
// ---------------------------------------------------------------------------
extern "C" void kernel_launch(void* const* d_in, const int* in_sizes, int n_in,
                              void* d_out, int out_size, void* d_ws, size_t ws_size,
                              hipStream_t stream){
  (void)in_sizes; (void)n_in; (void)out_size; (void)ws_size;
  const float* xyz   = (const float*)d_in[0];
  const float* feats = (const float*)d_in[1];
  const float* w1  = (const float*)d_in[2];
  const float* b1  = (const float*)d_in[3];
  const float* g1  = (const float*)d_in[4];
  const float* bt1 = (const float*)d_in[5];
  const float* w2  = (const float*)d_in[6];
  const float* b2  = (const float*)d_in[7];
  const float* g2  = (const float*)d_in[8];
  const float* bt2 = (const float*)d_in[9];
  const float* w3  = (const float*)d_in[10];
  const float* b3  = (const float*)d_in[11];
  const float* g3  = (const float*)d_in[12];
  const float* bt3 = (const float*)d_in[13];
  float* out = (float*)d_out;

  float* X  = (float*)d_ws;
  float* Y  = X + kB*kN;
  float* Z  = Y + kB*kN;
  int*   ci = (int*)(Z + kB*kN);
  u16*   bi = (u16*)(ci + kB*kS);

  hipLaunchKernelGGL(prep_kernel,  dim3(256),  dim3(256), 0, stream, xyz, X, Y, Z);
  hipLaunchKernelGGL(fps_kernel,   dim3(kB),   dim3(512), 0, stream, X, Y, Z, ci, out);
  hipLaunchKernelGGL(ballq_kernel, dim3(4096), dim3(256), 0, stream, X, Y, Z, ci, bi);
  hipLaunchKernelGGL(mlp_kernel,   dim3(512),  dim3(256), 0, stream,
                     feats, w1, b1, g1, bt1, w2, b2, g2, bt2, w3, b3, g3, bt3,
                     X, Y, Z, ci, bi, out + (size_t)kB*kS*3);
}